// Round 2
// baseline (207.478 us; speedup 1.0000x reference)
//
#include <hip/hip_runtime.h>

// MultiHeadedTrilinearAttention, MI355X fp32 implementation (round 2).
// B=1, S=128, DIM=768, H=12, W=64. Softmax groups = contiguous 4096 scores;
// outputs collapse to 48 marginal sums per group (trailing reshape dim = 1).
// ws usage: 6 * 128*768 floats = 2,359,296 bytes (vp,qp,ap,vo,qo,ao).

#define DIM   768
#define SEQ   128
#define NH    12
#define HW    64
#define PROJ_ELEMS (SEQ * DIM)   // 98304
#define QOUT_OFF   98304
#define AOUT_OFF   196608

// -------- bias init: C[i,j] = b[j] for all six projection buffers --------
__global__ __launch_bounds__(256) void init_bias_kernel(
    float* __restrict__ c0, float* __restrict__ c1, float* __restrict__ c2,
    float* __restrict__ c3, float* __restrict__ c4, float* __restrict__ c5,
    const float* __restrict__ b0, const float* __restrict__ b1, const float* __restrict__ b2,
    const float* __restrict__ b3, const float* __restrict__ b4, const float* __restrict__ b5)
{
    const int y = blockIdx.y;
    float* dst = (y == 0) ? c0 : (y == 1) ? c1 : (y == 2) ? c2
               : (y == 3) ? c3 : (y == 4) ? c4 : c5;
    const float* bb = (y == 0) ? b0 : (y == 1) ? b1 : (y == 2) ? b2
                    : (y == 3) ? b3 : (y == 4) ? b4 : b5;
    const int i4 = blockIdx.x * 256 + threadIdx.x;        // 0..24575 float4s
    const int col4 = (i4 % (DIM / 4)) * 4;
    ((float4*)dst)[i4] = *(const float4*)&bb[col4];
}

// -------- split-K projection GEMM with fp32 atomic accumulation ----------
// C[128,768] += A[128,768] @ W[768,768], K split 4 ways (192 each).
// 64x64 tile, 4x4 micro-tile, BK=32, LDS double buffer. 2x12x12 grid.
__global__ __launch_bounds__(256) void proj_splitk_kernel(
    const float* __restrict__ A0, const float* __restrict__ A1, const float* __restrict__ A2,
    const float* __restrict__ W0, const float* __restrict__ W1, const float* __restrict__ W2,
    float* __restrict__ C0, float* __restrict__ C1, float* __restrict__ C2)
{
    const int z   = blockIdx.z;
    const int mat = z >> 2;              // 0..2
    const int ks  = z & 3;               // K slice 0..3
    const float* __restrict__ A  = (mat == 0) ? A0 : (mat == 1) ? A1 : A2;
    const float* __restrict__ Wm = (mat == 0) ? W0 : (mat == 1) ? W1 : W2;
    float* __restrict__ C        = (mat == 0) ? C0 : (mat == 1) ? C1 : C2;

    const int m0 = blockIdx.x * 64;
    const int n0 = blockIdx.y * 64;
    const int kb0 = ks * 192;

    __shared__ float As[2][32][68];      // [buf][k][m]
    __shared__ float Bs[2][32][68];      // [buf][k][n]

    const int t  = threadIdx.x;
    const int ar = t >> 2;               // A stage row 0..63
    const int ac = t & 3;                // A stage float4-chunk (and +4)
    const int bk = t >> 4;               // B stage k 0..15 (and +16)
    const int bn = (t & 15) << 2;        // B stage col 0..60
    const int ty = t >> 4;               // out rows 4ty..4ty+3
    const int tx = t & 15;               // out cols 4tx..4tx+3

    float acc[4][4];
    #pragma unroll
    for (int i = 0; i < 4; ++i)
        #pragma unroll
        for (int j = 0; j < 4; ++j) acc[i][j] = 0.f;

    float4 av0 = *(const float4*)&A [(m0 + ar) * DIM + kb0 + 4 * ac];
    float4 av1 = *(const float4*)&A [(m0 + ar) * DIM + kb0 + 4 * (ac + 4)];
    float4 bv0 = *(const float4*)&Wm[(kb0 + bk     ) * DIM + n0 + bn];
    float4 bv1 = *(const float4*)&Wm[(kb0 + bk + 16) * DIM + n0 + bn];
    #pragma unroll
    for (int j = 0; j < 4; ++j) {
        As[0][4 * ac + j][ar]       = ((const float*)&av0)[j];
        As[0][4 * (ac + 4) + j][ar] = ((const float*)&av1)[j];
    }
    *(float4*)&Bs[0][bk     ][bn] = bv0;
    *(float4*)&Bs[0][bk + 16][bn] = bv1;

    const int NSTEP = 6;                 // 192 / 32
    for (int s = 0; s < NSTEP; ++s) {
        __syncthreads();
        if (s + 1 < NSTEP) {
            const int k0 = kb0 + (s + 1) * 32;
            av0 = *(const float4*)&A [(m0 + ar) * DIM + k0 + 4 * ac];
            av1 = *(const float4*)&A [(m0 + ar) * DIM + k0 + 4 * (ac + 4)];
            bv0 = *(const float4*)&Wm[(k0 + bk     ) * DIM + n0 + bn];
            bv1 = *(const float4*)&Wm[(k0 + bk + 16) * DIM + n0 + bn];
        }
        const int cur = s & 1;
        #pragma unroll
        for (int k = 0; k < 32; ++k) {
            const float4 af = *(const float4*)&As[cur][k][4 * ty];
            const float4 bf = *(const float4*)&Bs[cur][k][4 * tx];
            #pragma unroll
            for (int i = 0; i < 4; ++i) {
                const float a = ((const float*)&af)[i];
                acc[i][0] += a * bf.x;
                acc[i][1] += a * bf.y;
                acc[i][2] += a * bf.z;
                acc[i][3] += a * bf.w;
            }
        }
        if (s + 1 < NSTEP) {
            const int nx = cur ^ 1;
            #pragma unroll
            for (int j = 0; j < 4; ++j) {
                As[nx][4 * ac + j][ar]       = ((const float*)&av0)[j];
                As[nx][4 * (ac + 4) + j][ar] = ((const float*)&av1)[j];
            }
            *(float4*)&Bs[nx][bk     ][bn] = bv0;
            *(float4*)&Bs[nx][bk + 16][bn] = bv1;
        }
    }

    #pragma unroll
    for (int i = 0; i < 4; ++i)
        #pragma unroll
        for (int j = 0; j < 4; ++j)
            atomicAdd(&C[(m0 + 4 * ty + i) * DIM + n0 + 4 * tx + j], acc[i][j]);
}

// map flat index of (H,S,W)-ordered "heads view" back into row-major (S,DIM)
__device__ __forceinline__ float fetch_o(const float* __restrict__ p, int idx) {
    return p[((idx >> 6) & 127) * DIM + (idx >> 13) * HW + (idx & 63)];
}

// -------- fused scores + group softmax + marginals + outputs --------
// block = (v-token, head); scores s[q][a] (128x128) for this (h,v).
// wave w == softmax group g = h*512 + v*4 + w  (q in [32w,32w+32)).
// a-columns per thread: {4tx..4tx+3} and {64+4tx..64+4tx+3}  (conflict-free).
__global__ __launch_bounds__(256) void fused_attn_kernel(
    const float* __restrict__ vp, const float* __restrict__ qp, const float* __restrict__ ap,
    const float* __restrict__ vo, const float* __restrict__ qo, const float* __restrict__ ao,
    float* __restrict__ out)
{
    const int vtok = blockIdx.x;   // 0..127
    const int h    = blockIdx.y;   // 0..11

    __shared__ float Al[32][128];  // [k][q] : vh[v,k]*qh[q,k]
    __shared__ float Bl[32][128];  // [k][a] : ah[a,k]

    const int t  = threadIdx.x;
    const int ty = t >> 4;         // q rows 8ty..8ty+7
    const int tx = t & 15;

    const int srow = t >> 1;          // staged token 0..127
    const int w0   = (t & 1) << 4;    // 0 / 16 within 32-wide k phase

    float acc[8][8];
    #pragma unroll
    for (int i = 0; i < 8; ++i)
        #pragma unroll
        for (int j = 0; j < 8; ++j) acc[i][j] = 0.f;

    #pragma unroll
    for (int ph = 0; ph < 2; ++ph) {
        const int base = h * HW + ph * 32 + w0;
        #pragma unroll
        for (int u = 0; u < 4; ++u) {
            const float4 qv = *(const float4*)&qp[srow * DIM + base + 4 * u];
            const float4 vv = *(const float4*)&vp[vtok * DIM + base + 4 * u];
            const float4 aa = *(const float4*)&ap[srow * DIM + base + 4 * u];
            const int wl = w0 + 4 * u;
            Al[wl + 0][srow] = qv.x * vv.x;
            Al[wl + 1][srow] = qv.y * vv.y;
            Al[wl + 2][srow] = qv.z * vv.z;
            Al[wl + 3][srow] = qv.w * vv.w;
            Bl[wl + 0][srow] = aa.x;
            Bl[wl + 1][srow] = aa.y;
            Bl[wl + 2][srow] = aa.z;
            Bl[wl + 3][srow] = aa.w;
        }
        __syncthreads();
        #pragma unroll 4
        for (int k = 0; k < 32; ++k) {
            float af[8], bf[8];
            *(float4*)&af[0] = *(const float4*)&Al[k][8 * ty];
            *(float4*)&af[4] = *(const float4*)&Al[k][8 * ty + 4];
            *(float4*)&bf[0] = *(const float4*)&Bl[k][4 * tx];        // a = 4tx+j
            *(float4*)&bf[4] = *(const float4*)&Bl[k][64 + 4 * tx];   // a = 64+4tx+j
            #pragma unroll
            for (int i = 0; i < 8; ++i)
                #pragma unroll
                for (int j = 0; j < 8; ++j)
                    acc[i][j] += af[i] * bf[j];
        }
        __syncthreads();
    }

    // scale 1/sqrt(64), wave(=group) max
    float mx = -1e30f;
    #pragma unroll
    for (int i = 0; i < 8; ++i)
        #pragma unroll
        for (int j = 0; j < 8; ++j) {
            acc[i][j] *= 0.125f;
            mx = fmaxf(mx, acc[i][j]);
        }
    #pragma unroll
    for (int d = 1; d < 64; d <<= 1) mx = fmaxf(mx, __shfl_xor(mx, d, 64));

    // exp + per-thread marginal partials.
    // group-local q'' = 8*(ty&3)+i; a = (j<4) ? 4tx+j : 64+4tx+(j&3)
    // i-bin = q''/2               = 4*(ty&3) + (i>>1)            -> sv[i>>1]
    // j-bin = (q''%2)*8 + a/16    = (i&1)*8 + (j>>2)*4 + (tx>>2) -> sq[i&1][j>>2]
    // k-bin = a%16                = 4*(tx&3) + (j&3)             -> sa[j&3]
    float sv[4] = {0.f, 0.f, 0.f, 0.f};
    float sq[2][2] = {{0.f, 0.f}, {0.f, 0.f}};
    float sa[4] = {0.f, 0.f, 0.f, 0.f};
    float tot = 0.f;
    #pragma unroll
    for (int i = 0; i < 8; ++i) {
        float rs = 0.f;
        #pragma unroll
        for (int j = 0; j < 8; ++j) {
            const float e = __expf(acc[i][j] - mx);
            rs += e;
            sa[j & 3] += e;
            sq[i & 1][j >> 2] += e;
        }
        sv[i >> 1] += rs;
        tot += rs;
    }

    // wave reductions. lane bits: b0,b1 = tx&3; b2,b3 = tx>>2; b4,b5 = ty&3
    #pragma unroll
    for (int d = 1; d < 64; d <<= 1) tot += __shfl_xor(tot, d, 64);
    #pragma unroll
    for (int dd = 0; dd < 4; ++dd) {          // sv: reduce b0..b3 (all tx)
        const int d = 1 << dd;
        #pragma unroll
        for (int p = 0; p < 4; ++p) sv[p] += __shfl_xor(sv[p], d, 64);
    }
    {   // sq: reduce b0,b1,b4,b5 (keep tx>>2)
        const int dls[4] = {1, 2, 16, 32};
        #pragma unroll
        for (int u = 0; u < 4; ++u) {
            const int d = dls[u];
            sq[0][0] += __shfl_xor(sq[0][0], d, 64);
            sq[0][1] += __shfl_xor(sq[0][1], d, 64);
            sq[1][0] += __shfl_xor(sq[1][0], d, 64);
            sq[1][1] += __shfl_xor(sq[1][1], d, 64);
        }
    }
    #pragma unroll
    for (int dd = 2; dd < 6; ++dd) {          // sa: reduce b2..b5 (keep tx&3)
        const int d = 1 << dd;
        #pragma unroll
        for (int c = 0; c < 4; ++c) sa[c] += __shfl_xor(sa[c], d, 64);
    }

    const int wv = t >> 6;
    const int l  = t & 63;
    const int g  = h * 512 + vtok * 4 + wv;   // softmax group id
    const int b2 = g / 12;
    const int h2 = g - b2 * 12;
    const float invZ = 1.0f / tot;

    if ((l & 15) == 0) {                      // l = 0,16,32,48 : 16 v-outputs
        const int tyl = l >> 4;
        #pragma unroll
        for (int p = 0; p < 4; ++p) {
            const int bin = tyl * 4 + p;
            const int idx = g * 16 + bin;
            out[(b2 * 16 + bin) * 12 + h2] = sv[p] * invZ * fetch_o(vo, idx);
        }
    }
    if ((l & 51) == 0) {                      // l = 0,4,8,12 : 16 q-outputs
        const int q2 = l >> 2;
        #pragma unroll
        for (int i1 = 0; i1 < 2; ++i1)
            #pragma unroll
            for (int hf = 0; hf < 2; ++hf) {
                const int bin = i1 * 8 + hf * 4 + q2;
                out[QOUT_OFF + (b2 * 16 + bin) * 12 + h2] =
                    sq[i1][hf] * invZ * fetch_o(qo, g * 16 + bin);
            }
    }
    if (l < 4) {                              // 16 a-outputs
        #pragma unroll
        for (int c = 0; c < 4; ++c) {
            const int bin = 4 * l + c;
            out[AOUT_OFF + (b2 * 16 + bin) * 12 + h2] =
                sa[c] * invZ * fetch_o(ao, g * 16 + bin);
        }
    }
}

extern "C" void kernel_launch(void* const* d_in, const int* in_sizes, int n_in,
                              void* d_out, int out_size, void* d_ws, size_t ws_size,
                              hipStream_t stream)
{
    const float* v   = (const float*)d_in[0];
    const float* q   = (const float*)d_in[1];
    const float* a   = (const float*)d_in[2];
    // d_in[3..5] = masks, unused by the reference forward
    const float* Wv  = (const float*)d_in[6];
    const float* bv  = (const float*)d_in[7];
    const float* Wq  = (const float*)d_in[8];
    const float* bq  = (const float*)d_in[9];
    const float* Wa  = (const float*)d_in[10];
    const float* ba  = (const float*)d_in[11];
    const float* Wvo = (const float*)d_in[12];
    const float* bvo = (const float*)d_in[13];
    const float* Wqo = (const float*)d_in[14];
    const float* bqo = (const float*)d_in[15];
    const float* Wao = (const float*)d_in[16];
    const float* bao = (const float*)d_in[17];

    float* out = (float*)d_out;
    float* ws  = (float*)d_ws;           // needs 6*98304 floats = 2.36 MB
    float* vp = ws + 0 * PROJ_ELEMS;
    float* qp = ws + 1 * PROJ_ELEMS;
    float* ap = ws + 2 * PROJ_ELEMS;
    float* vo = ws + 3 * PROJ_ELEMS;
    float* qo = ws + 4 * PROJ_ELEMS;
    float* ao = ws + 5 * PROJ_ELEMS;

    // C = bias (all six buffers), then split-K atomic accumulation
    init_bias_kernel<<<dim3(96, 6), 256, 0, stream>>>(
        vp, qp, ap, vo, qo, ao, bv, bq, ba, bvo, bqo, bao);
    proj_splitk_kernel<<<dim3(2, 12, 12), 256, 0, stream>>>(
        v, q, a, Wv, Wq, Wa, vp, qp, ap);
    proj_splitk_kernel<<<dim3(2, 12, 12), 256, 0, stream>>>(
        vp, qp, ap, Wvo, Wqo, Wao, vo, qo, ao);
    fused_attn_kernel<<<dim3(SEQ, NH), 256, 0, stream>>>(
        vp, qp, ap, vo, qo, ao, out);
}

// Round 3
// 150.477 us; speedup vs baseline: 1.3788x; 1.3788x over previous
//
#include <hip/hip_runtime.h>

// MultiHeadedTrilinearAttention, MI355X — round 3: bf16 MFMA everywhere.
// B=1, S=128, DIM=768, H=12, W=64. Softmax groups = contiguous 4096 scores
// (g = h*512 + v*4 + q>>5, verified passing in rounds 1-2); outputs collapse
// to 48 marginal sums per group. ws: 6 * 128*768 fp32 = 2,359,296 bytes.

#define DIM   768
#define SEQ   128
#define NH    12
#define HW    64
#define PROJ_ELEMS (SEQ * DIM)   // 98304
#define QOUT_OFF   98304
#define AOUT_OFF   196608

typedef short bf16x8 __attribute__((ext_vector_type(8)));
typedef short bf16x4 __attribute__((ext_vector_type(4)));
typedef float f32x4  __attribute__((ext_vector_type(4)));

__device__ __forceinline__ short f2bf(float f) {
    unsigned u = __float_as_uint(f);
    u = (u + 0x7FFFu + ((u >> 16) & 1u)) >> 16;   // RNE
    return (short)u;
}

// ---------------- projection GEMM via MFMA ----------------
// C[128,768] = A[128,768] @ W[768,768] + b.  Tile: full M=128 x 32 N, K=768.
// A-frags straight from global (fp32 -> bf16 in regs); W transposed to
// LDS [n][k] bf16, double-buffered. Grid: 24 n-tiles x 3 matrices.
__global__ __launch_bounds__(256) void proj_mfma_kernel(
    const float* __restrict__ A0, const float* __restrict__ A1, const float* __restrict__ A2,
    const float* __restrict__ W0, const float* __restrict__ W1, const float* __restrict__ W2,
    const float* __restrict__ b0, const float* __restrict__ b1, const float* __restrict__ b2,
    float* __restrict__ C0, float* __restrict__ C1, float* __restrict__ C2)
{
    const int mat = blockIdx.y;
    const float* __restrict__ A  = (mat == 0) ? A0 : (mat == 1) ? A1 : A2;
    const float* __restrict__ Wm = (mat == 0) ? W0 : (mat == 1) ? W1 : W2;
    const float* __restrict__ bb = (mat == 0) ? b0 : (mat == 1) ? b1 : b2;
    float* __restrict__ C        = (mat == 0) ? C0 : (mat == 1) ? C1 : C2;
    const int n0 = blockIdx.x * 32;

    __shared__ short Bl[2][32][136];   // [buf][n][k], pad 136 (16B multiple)

    const int t    = threadIdx.x;
    const int w    = t >> 6;           // wave 0..3 -> m rows [32w, 32w+32)
    const int lane = t & 63;
    const int fm   = lane & 15;        // fragment outer index (m or n)
    const int fk   = (lane >> 4) << 3; // fragment k offset (0,8,16,24)

    // W staging: thread t handles 4k x 4n patch (k0 = 4*(t>>3), n = 4*(t&7))
    const int kp = (t >> 3) << 2;      // 0..124
    const int np = (t & 7) << 2;       // 0..28

    f32x4 acc[2][2];
    #pragma unroll
    for (int mt = 0; mt < 2; ++mt)
        #pragma unroll
        for (int nt = 0; nt < 2; ++nt)
            acc[mt][nt] = (f32x4){0.f, 0.f, 0.f, 0.f};

    f32x4 wr[4];
    #pragma unroll
    for (int rr = 0; rr < 4; ++rr)
        wr[rr] = *(const f32x4*)&Wm[(kp + rr) * DIM + n0 + np];

    for (int s = 0; s < 6; ++s) {
        // prefetch W for next kstep
        f32x4 wn[4];
        if (s < 5) {
            #pragma unroll
            for (int rr = 0; rr < 4; ++rr)
                wn[rr] = *(const f32x4*)&Wm[((s + 1) * 128 + kp + rr) * DIM + n0 + np];
        }
        // A-fragment loads for this kstep (fp32, L2-hot)
        f32x4 alo[2][4], ahi[2][4];
        #pragma unroll
        for (int mt = 0; mt < 2; ++mt)
            #pragma unroll
            for (int ks = 0; ks < 4; ++ks) {
                const float* pa = &A[(32 * w + 16 * mt + fm) * DIM + s * 128 + 32 * ks + fk];
                alo[mt][ks] = *(const f32x4*)pa;
                ahi[mt][ks] = *(const f32x4*)(pa + 4);
            }
        // transpose-convert W patch into LDS buf (s&1)
        const int buf = s & 1;
        #pragma unroll
        for (int c = 0; c < 4; ++c) {
            bf16x4 pk;
            pk[0] = f2bf(wr[0][c]); pk[1] = f2bf(wr[1][c]);
            pk[2] = f2bf(wr[2][c]); pk[3] = f2bf(wr[3][c]);
            *(bf16x4*)&Bl[buf][np + c][kp] = pk;
        }
        __syncthreads();
        #pragma unroll
        for (int ks = 0; ks < 4; ++ks) {
            bf16x8 bfr0 = *(const bf16x8*)&Bl[buf][fm     ][32 * ks + fk];
            bf16x8 bfr1 = *(const bf16x8*)&Bl[buf][16 + fm][32 * ks + fk];
            #pragma unroll
            for (int mt = 0; mt < 2; ++mt) {
                bf16x8 afr;
                afr[0] = f2bf(alo[mt][ks][0]); afr[1] = f2bf(alo[mt][ks][1]);
                afr[2] = f2bf(alo[mt][ks][2]); afr[3] = f2bf(alo[mt][ks][3]);
                afr[4] = f2bf(ahi[mt][ks][0]); afr[5] = f2bf(ahi[mt][ks][1]);
                afr[6] = f2bf(ahi[mt][ks][2]); afr[7] = f2bf(ahi[mt][ks][3]);
                acc[mt][0] = __builtin_amdgcn_mfma_f32_16x16x32_bf16(afr, bfr0, acc[mt][0], 0, 0, 0);
                acc[mt][1] = __builtin_amdgcn_mfma_f32_16x16x32_bf16(afr, bfr1, acc[mt][1], 0, 0, 0);
            }
        }
        #pragma unroll
        for (int rr = 0; rr < 4; ++rr) wr[rr] = wn[rr];
    }

    // epilogue: C row = 32w + 16mt + quad*4 + r, col = n0 + 16nt + fm
    const int quad4 = (lane >> 4) << 2;
    #pragma unroll
    for (int mt = 0; mt < 2; ++mt) {
        const int row0 = 32 * w + 16 * mt + quad4;
        #pragma unroll
        for (int nt = 0; nt < 2; ++nt) {
            const int col  = n0 + 16 * nt + fm;
            const float bi = bb[col];
            #pragma unroll
            for (int rr = 0; rr < 4; ++rr)
                C[(row0 + rr) * DIM + col] = acc[mt][nt][rr] + bi;
        }
    }
}

// map flat index of (H,S,W)-ordered "heads view" back into row-major (S,DIM)
__device__ __forceinline__ float fetch_o(const float* __restrict__ p, int idx) {
    return p[((idx >> 6) & 127) * DIM + (idx >> 13) * HW + (idx & 63)];
}

// -------- fused MFMA scores + group softmax + marginals + outputs --------
// block = (v-token, head). S[q][a] = sum_k vq[q,k]*ah[a,k], 128x128x64 bf16.
// wave w == softmax group (q in [32w,32w+32)).
// MFMA C layout: col a = at*16 + (lane&15); row q'' = qt*16 + quad*4 + reg.
__global__ __launch_bounds__(256) void fused_attn_kernel(
    const float* __restrict__ vp, const float* __restrict__ qp, const float* __restrict__ ap,
    const float* __restrict__ vo, const float* __restrict__ qo, const float* __restrict__ ao,
    float* __restrict__ out)
{
    const int vtok = blockIdx.x;   // 0..127
    const int h    = blockIdx.y;   // 0..11

    __shared__ short vqL[128][72]; // [q][k] bf16, pad 72
    __shared__ short ahL[128][72]; // [a][k] bf16

    const int t    = threadIdx.x;
    const int w    = t >> 6;
    const int lane = t & 63;
    const int fm   = lane & 15;
    const int fk   = (lane >> 4) << 3;

    // staging: thread t -> row r = t>>1, k-half hh = (t&1)*32
    {
        const int r     = t >> 1;
        const int hh    = (t & 1) << 5;
        const int gcol  = h * HW + hh;
        bf16x8 vqpk[4], ahpk[4];
        #pragma unroll
        for (int u = 0; u < 8; ++u) {
            f32x4 q4 = *(const f32x4*)&qp[r    * DIM + gcol + 4 * u];
            f32x4 v4 = *(const f32x4*)&vp[vtok * DIM + gcol + 4 * u];
            f32x4 a4 = *(const f32x4*)&ap[r    * DIM + gcol + 4 * u];
            #pragma unroll
            for (int c = 0; c < 4; ++c) {
                const int idx = 4 * u + c;
                vqpk[idx >> 3][idx & 7] = f2bf(q4[c] * v4[c]);
                ahpk[idx >> 3][idx & 7] = f2bf(a4[c]);
            }
        }
        #pragma unroll
        for (int u2 = 0; u2 < 4; ++u2) {
            *(bf16x8*)&vqL[r][hh + 8 * u2] = vqpk[u2];
            *(bf16x8*)&ahL[r][hh + 8 * u2] = ahpk[u2];
        }
    }
    __syncthreads();

    f32x4 acc[2][8];
    #pragma unroll
    for (int qt = 0; qt < 2; ++qt)
        #pragma unroll
        for (int at = 0; at < 8; ++at)
            acc[qt][at] = (f32x4){0.f, 0.f, 0.f, 0.f};

    const int q0 = 32 * w;
    #pragma unroll
    for (int ks = 0; ks < 2; ++ks) {
        bf16x8 afr0 = *(const bf16x8*)&vqL[q0 + fm     ][32 * ks + fk];
        bf16x8 afr1 = *(const bf16x8*)&vqL[q0 + 16 + fm][32 * ks + fk];
        #pragma unroll
        for (int at = 0; at < 8; ++at) {
            bf16x8 bfr = *(const bf16x8*)&ahL[16 * at + fm][32 * ks + fk];
            acc[0][at] = __builtin_amdgcn_mfma_f32_16x16x32_bf16(afr0, bfr, acc[0][at], 0, 0, 0);
            acc[1][at] = __builtin_amdgcn_mfma_f32_16x16x32_bf16(afr1, bfr, acc[1][at], 0, 0, 0);
        }
    }

    // scale by 1/sqrt(64) and wave max
    float mx = -1e30f;
    #pragma unroll
    for (int qt = 0; qt < 2; ++qt)
        #pragma unroll
        for (int at = 0; at < 8; ++at)
            #pragma unroll
            for (int rr = 0; rr < 4; ++rr) {
                acc[qt][at][rr] *= 0.125f;
                mx = fmaxf(mx, acc[qt][at][rr]);
            }
    #pragma unroll
    for (int d = 1; d < 64; d <<= 1) mx = fmaxf(mx, __shfl_xor(mx, d, 64));

    // exp + marginal partials.
    // q'' = qt*16 + quad*4 + rr ; a = at*16 + fm
    // i-bin = q''>>1 = qt*8 + quad*2 + (rr>>1)   -> sv[qt][rr>>1] (quad in lane)
    // j-bin = (rr&1)*8 + at                      -> sq[rr&1][at]  (lane-uniform)
    // k-bin = fm                                 -> sa            (fm in lane)
    float sv[2][2] = {{0.f, 0.f}, {0.f, 0.f}};
    float sq[2][8];
    #pragma unroll
    for (int i = 0; i < 2; ++i)
        #pragma unroll
        for (int j = 0; j < 8; ++j) sq[i][j] = 0.f;
    float sa = 0.f;
    #pragma unroll
    for (int qt = 0; qt < 2; ++qt)
        #pragma unroll
        for (int at = 0; at < 8; ++at)
            #pragma unroll
            for (int rr = 0; rr < 4; ++rr) {
                const float e = __expf(acc[qt][at][rr] - mx);
                sv[qt][rr >> 1] += e;
                sq[rr & 1][at]  += e;
                sa += e;
            }
    float tot = sv[0][0] + sv[0][1] + sv[1][0] + sv[1][1];

    #pragma unroll
    for (int d = 1; d < 64; d <<= 1) tot += __shfl_xor(tot, d, 64);
    #pragma unroll
    for (int dd = 0; dd < 4; ++dd) {          // sv: reduce lane bits 0..3 (fm)
        const int d = 1 << dd;
        #pragma unroll
        for (int qt = 0; qt < 2; ++qt)
            #pragma unroll
            for (int rh = 0; rh < 2; ++rh)
                sv[qt][rh] += __shfl_xor(sv[qt][rh], d, 64);
    }
    #pragma unroll
    for (int dd = 0; dd < 6; ++dd) {          // sq: full wave reduce
        const int d = 1 << dd;
        #pragma unroll
        for (int i = 0; i < 2; ++i)
            #pragma unroll
            for (int j = 0; j < 8; ++j)
                sq[i][j] += __shfl_xor(sq[i][j], d, 64);
    }
    sa += __shfl_xor(sa, 16, 64);             // sa: reduce lane bits 4..5 (quad)
    sa += __shfl_xor(sa, 32, 64);

    const int g  = h * 512 + vtok * 4 + w;    // softmax group id
    const int b2 = g / 12;
    const int h2 = g - b2 * 12;
    const float invZ = 1.0f / tot;

    if (fm == 0) {                            // lanes 0,16,32,48: 16 v-outputs
        const int quad = lane >> 4;
        #pragma unroll
        for (int qt = 0; qt < 2; ++qt)
            #pragma unroll
            for (int rh = 0; rh < 2; ++rh) {
                const int bin = qt * 8 + quad * 2 + rh;
                out[(b2 * 16 + bin) * 12 + h2] =
                    sv[qt][rh] * invZ * fetch_o(vo, g * 16 + bin);
            }
    }
    if (lane == 0) {                          // 16 q-outputs
        #pragma unroll
        for (int i = 0; i < 2; ++i)
            #pragma unroll
            for (int j = 0; j < 8; ++j) {
                const int bin = i * 8 + j;
                out[QOUT_OFF + (b2 * 16 + bin) * 12 + h2] =
                    sq[i][j] * invZ * fetch_o(qo, g * 16 + bin);
            }
    }
    if (lane < 16) {                          // 16 a-outputs
        out[AOUT_OFF + (b2 * 16 + lane) * 12 + h2] =
            sa * invZ * fetch_o(ao, g * 16 + lane);
    }
}

extern "C" void kernel_launch(void* const* d_in, const int* in_sizes, int n_in,
                              void* d_out, int out_size, void* d_ws, size_t ws_size,
                              hipStream_t stream)
{
    const float* v   = (const float*)d_in[0];
    const float* q   = (const float*)d_in[1];
    const float* a   = (const float*)d_in[2];
    // d_in[3..5] = masks, unused by the reference forward
    const float* Wv  = (const float*)d_in[6];
    const float* bv  = (const float*)d_in[7];
    const float* Wq  = (const float*)d_in[8];
    const float* bq  = (const float*)d_in[9];
    const float* Wa  = (const float*)d_in[10];
    const float* ba  = (const float*)d_in[11];
    const float* Wvo = (const float*)d_in[12];
    const float* bvo = (const float*)d_in[13];
    const float* Wqo = (const float*)d_in[14];
    const float* bqo = (const float*)d_in[15];
    const float* Wao = (const float*)d_in[16];
    const float* bao = (const float*)d_in[17];

    float* out = (float*)d_out;
    float* ws  = (float*)d_ws;           // needs 6*98304 floats = 2.36 MB
    float* vp = ws + 0 * PROJ_ELEMS;
    float* qp = ws + 1 * PROJ_ELEMS;
    float* ap = ws + 2 * PROJ_ELEMS;
    float* vo = ws + 3 * PROJ_ELEMS;
    float* qo = ws + 4 * PROJ_ELEMS;
    float* ao = ws + 5 * PROJ_ELEMS;

    proj_mfma_kernel<<<dim3(24, 3), 256, 0, stream>>>(
        v, q, a, Wv, Wq, Wa, bv, bq, ba, vp, qp, ap);
    proj_mfma_kernel<<<dim3(24, 3), 256, 0, stream>>>(
        vp, qp, ap, Wvo, Wqo, Wao, bvo, bqo, bao, vo, qo, ao);
    fused_attn_kernel<<<dim3(SEQ, NH), 256, 0, stream>>>(
        vp, qp, ap, vo, qo, ao, out);
}